// Round 9
// baseline (230.241 us; speedup 1.0000x reference)
//
#include <hip/hip_runtime.h>
#include <hip/hip_fp16.h>

#define N_NODES 50000
#define N_EDGES 800000
#define D 64

#define SLICES 100                 // edge slices per role (src/dst)
#define I4S    2000                // int4 per slice (8000 edges)
#define NI4    200000              // total int4 per role
#define NWORDS 12512               // ceil(50000/4)=12500, padded to /4
#define MBLK   1024                // mega-kernel grid
#define MERGE_BLOCKS 49            // 49*256 = 12544 >= 12500 merge threads

typedef float vfloat2 __attribute__((ext_vector_type(2)));

// ---------------------------------------------------------------------------
// Workspace layout (bytes), ~21 MB, offsets 256-aligned:
//   [0,        4)          ctr    : int (scan counter; zeroed by degree pass)
//   [64,       68)         gate   : int (phase gate;   zeroed by degree pass)
//   [256,      400256)     meta   : int2[N_NODES]  (.x = CSR base, .y = indeg)
//   [400384,   600384)     snorm  : float[N_NODES]
//   [600576,   3800576)    ssrc   : int[N_EDGES]   src ids grouped by dst
//   [3800576,  4600576)    occ    : uchar[N_EDGES] within-slice occurrence
//   [4600832,  14610432)   partial: uint[200][NWORDS] byte hists -> prefixes
//   [14610432, 17810432)   yA     : half[N_NODES*32] features  0..31
//   [17810688, 21010688)   yB     : half[N_NODES*32] features 32..63
// ---------------------------------------------------------------------------
#define CTR_OFF    0
#define GATE_OFF   64
#define META_OFF   256
#define SNORM_OFF  400384
#define SSRC_OFF   600576
#define OCC_OFF    3800576
#define PART_OFF   4600832
#define YA_OFF     14610432
#define YB_OFF     17810688

// ---------------------------------------------------------------------------
// Pass 1: per-slice byte-packed degree histograms in LDS (no fabric atomics).
// dst-role blocks also record each edge's within-slice occurrence byte.
// Block 0 zeroes the scan counter and the gate.
// ---------------------------------------------------------------------------
__global__ __launch_bounds__(256) void degree_occ_kernel(const int4* __restrict__ src4,
                                                         const int4* __restrict__ dst4,
                                                         unsigned int* __restrict__ partial,
                                                         uchar4* __restrict__ occ4,
                                                         int* __restrict__ ctr,
                                                         int* __restrict__ gate) {
    __shared__ unsigned int hist[NWORDS];
    int tid = threadIdx.x;
    if (blockIdx.x == 0 && tid == 0) { *ctr = 0; *gate = 0; }
    uint4* h4 = (uint4*)hist;
    for (int i = tid; i < NWORDS / 4; i += 256) h4[i] = make_uint4(0, 0, 0, 0);
    __syncthreads();

    int role  = blockIdx.x & 1;
    int slice = blockIdx.x >> 1;
    int beg = slice * I4S, end = beg + I4S;
    if (role == 0) {
        for (int i = beg + tid; i < end; i += 256) {
            int4 v = src4[i];
            atomicAdd(&hist[v.x >> 2], 1u << ((v.x & 3) * 8));
            atomicAdd(&hist[v.y >> 2], 1u << ((v.y & 3) * 8));
            atomicAdd(&hist[v.z >> 2], 1u << ((v.z & 3) * 8));
            atomicAdd(&hist[v.w >> 2], 1u << ((v.w & 3) * 8));
        }
    } else {
        for (int i = beg + tid; i < end; i += 256) {
            int4 v = dst4[i];
            unsigned int o0 = (atomicAdd(&hist[v.x >> 2], 1u << ((v.x & 3) * 8)) >> ((v.x & 3) * 8)) & 0xFFu;
            unsigned int o1 = (atomicAdd(&hist[v.y >> 2], 1u << ((v.y & 3) * 8)) >> ((v.y & 3) * 8)) & 0xFFu;
            unsigned int o2 = (atomicAdd(&hist[v.z >> 2], 1u << ((v.z & 3) * 8)) >> ((v.z & 3) * 8)) & 0xFFu;
            unsigned int o3 = (atomicAdd(&hist[v.w >> 2], 1u << ((v.w & 3) * 8)) >> ((v.w & 3) * 8)) & 0xFFu;
            occ4[i] = make_uchar4((unsigned char)o0, (unsigned char)o1,
                                  (unsigned char)o2, (unsigned char)o3);
        }
    }
    __syncthreads();

    uint4* p4 = (uint4*)(partial + (size_t)blockIdx.x * NWORDS);
    for (int i = tid; i < NWORDS / 4; i += 256) p4[i] = h4[i];
}

// ---------------------------------------------------------------------------
// Pass 2 (mega: merge+scan -> gate -> fill + y), one dispatch, 1024 blocks.
//   Phase A (blocks 0..48): sum packed degrees over slices, rewrite dst-role
//     partials in place to per-slice EXCLUSIVE prefixes, wave-scan -> CSR
//     bases; write meta=(base,indeg) and snorm. threadfence + gate++.
//   Gate: all blocks spin (relaxed atomic poll + s_sleep) until gate==49,
//     then threadfence (acquire side). Deadlock-free: merge blocks have no
//     cross-block deps; gate is monotonic.
//   Phase B: CSR fill — fully parallel, no LDS, no atomics
//     (p = meta.x + slice prefix byte + occ byte). Inputs prefetched pre-gate.
//   Phase C: y = (x*snorm) @ W stored fp16 into yA/yB feature halves.
// ---------------------------------------------------------------------------
__global__ __launch_bounds__(256, 4) void mega_kernel(const int4* __restrict__ src4,
                                                      const int4* __restrict__ dst4,
                                                      const uchar4* __restrict__ occ4,
                                                      unsigned int* __restrict__ partial,
                                                      int2* __restrict__ meta,
                                                      float* __restrict__ snorm,
                                                      int* __restrict__ ctr,
                                                      int* __restrict__ gate,
                                                      int* __restrict__ ssrc,
                                                      const float* __restrict__ x,
                                                      const float* __restrict__ W,
                                                      __half* __restrict__ yA,
                                                      __half* __restrict__ yB) {
    int tid = blockIdx.x * blockDim.x + threadIdx.x;
    int lane = threadIdx.x & 63;

    // Prefetch fill inputs (do NOT depend on merge output).
    int4 sv, tv; uchar4 oc;
    bool havefill = (tid < NI4);
    if (havefill) { sv = src4[tid]; tv = dst4[tid]; oc = occ4[tid]; }

    // ---- Phase A: merge + scan (blocks 0..48) ----
    if (blockIdx.x < MERGE_BLOCKS) {
        int w = tid;
        unsigned int accin = 0, accout = 0;
        bool act = (w < 12500);
        if (act) {
            unsigned int* po = partial + w;            // src role: slot 2s
            unsigned int* pd = partial + NWORDS + w;   // dst role: slot 2s+1
#pragma unroll 4
            for (int s = 0; s < SLICES; s++) {
                size_t off = (size_t)(2 * s) * NWORDS;
                accout += po[off];
                unsigned int v = pd[off];
                pd[off] = accin;                       // exclusive prefix
                accin += v;
            }
        }
        int d0 = accin & 0xFF, d1 = (accin >> 8) & 0xFF,
            d2 = (accin >> 16) & 0xFF, d3 = (accin >> 24) & 0xFF;
        int tsum = d0 + d1 + d2 + d3;
        int run = tsum;  // inclusive wave scan
#pragma unroll
        for (int off = 1; off < 64; off <<= 1) {
            int v = __shfl_up(run, off);
            if (lane >= off) run += v;
        }
        int wtot = __shfl(run, 63);
        int wbase = 0;
        if (lane == 63) wbase = atomicAdd(ctr, wtot);
        wbase = __shfl(wbase, 63);
        if (act) {
            int b0 = wbase + run - tsum;
            int b1 = b0 + d0, b2 = b1 + d1, b3 = b2 + d2;
            ((int4*)meta)[2 * w]     = make_int4(b0, d0, b1, d1);
            ((int4*)meta)[2 * w + 1] = make_int4(b2, d2, b3, d3);
            int o0 = accout & 0xFF, o1 = (accout >> 8) & 0xFF,
                o2 = (accout >> 16) & 0xFF, o3 = (accout >> 24) & 0xFF;
            ((float4*)snorm)[w] = make_float4(rsqrtf(fmaxf((float)o0, 1.f)),
                                              rsqrtf(fmaxf((float)o1, 1.f)),
                                              rsqrtf(fmaxf((float)o2, 1.f)),
                                              rsqrtf(fmaxf((float)o3, 1.f)));
        }
        __threadfence();        // release: flush merge results
        __syncthreads();        // whole block done before signaling
        if (threadIdx.x == 0) atomicAdd(gate, 1);
    }

    // ---- Gate ----
    if (threadIdx.x == 0) {
        while (atomicAdd(gate, 0) < MERGE_BLOCKS) __builtin_amdgcn_s_sleep(8);
    }
    __syncthreads();
    __threadfence();            // acquire: invalidate stale cached lines

    // ---- Phase B: CSR fill ----
    if (havefill) {
        int s = tid / I4S;
        const unsigned int* pref = partial + (size_t)(2 * s + 1) * NWORDS;
#define FILL_ONE(T, S, O)                                                     \
        {                                                                     \
            int t = (T); int sh = (t & 3) * 8;                                \
            int p = meta[t].x + (int)((pref[t >> 2] >> sh) & 0xFFu) + (int)(O); \
            ssrc[p] = (S);                                                    \
        }
        FILL_ONE(tv.x, sv.x, oc.x)
        FILL_ONE(tv.y, sv.y, oc.y)
        FILL_ONE(tv.z, sv.z, oc.z)
        FILL_ONE(tv.w, sv.w, oc.w)
#undef FILL_ONE
    }

    // ---- Phase C: y = (x * snorm) @ W, fp16, feature-split halves ----
    float Wreg[D];
#pragma unroll
    for (int k = 0; k < D; k++) Wreg[k] = W[k * D + lane];
    __half* yh = (lane < 32) ? yA : yB;   // uniform per half-wave
    int jl = lane & 31;
    int wave = tid >> 6;
    const int nwaves = MBLK * 4;
    for (int n = wave; n < N_NODES; n += nwaves) {
        float hv = x[(size_t)n * D + lane] * snorm[n];
        int hb = __float_as_int(hv);
        float p0 = 0.f, p1 = 0.f, p2 = 0.f, p3 = 0.f;
#pragma unroll
        for (int k = 0; k < D; k += 4) {
            p0 = fmaf(__int_as_float(__builtin_amdgcn_readlane(hb, k + 0)), Wreg[k + 0], p0);
            p1 = fmaf(__int_as_float(__builtin_amdgcn_readlane(hb, k + 1)), Wreg[k + 1], p1);
            p2 = fmaf(__int_as_float(__builtin_amdgcn_readlane(hb, k + 2)), Wreg[k + 2], p2);
            p3 = fmaf(__int_as_float(__builtin_amdgcn_readlane(hb, k + 3)), Wreg[k + 3], p3);
        }
        yh[(size_t)n * 32 + jl] = __float2half((p0 + p1) + (p2 + p3));
    }
}

// ---------------------------------------------------------------------------
// Pass 3: out[n] = rsqrt(indeg) * sum_{in-edges} y[src] + b, by feature half.
// pass = blockIdx&1 (XCD partition of yA/yB); lane = (q = edge-of-4, c =
// half2 chunk): one wave-load = 4 rows. shfl ^16/^32 reduce; nontemporal
// float2 stores. meta packs (base,indeg) -> one 8B load/node, dnorm computed.
// ---------------------------------------------------------------------------
#define GBLK 2048
__global__ __launch_bounds__(256, 8) void gather_kernel(const __half2* __restrict__ yA,
                                                        const __half2* __restrict__ yB,
                                                        const int* __restrict__ ssrc,
                                                        const int2* __restrict__ meta,
                                                        const float* __restrict__ bias,
                                                        float* __restrict__ out) {
    int lane = threadIdx.x & 63;
    int q = lane >> 4;
    int c = lane & 15;
    int pass = blockIdx.x & 1;         // 0 -> yA, 1 -> yB
    int pblk = blockIdx.x >> 1;
    int wave = (pblk << 2) | (threadIdx.x >> 6);
    const int nwaves = (GBLK / 2) * 4;

    float2 b2 = ((const float2*)bias)[(pass << 4) + c];
    const __half2* ycol = (pass ? yB : yA) + c;   // row stride = 16 half2

#define ACC(A, F) { (A).x += (F).x; (A).y += (F).y; }

    for (int n = wave; n < N_NODES; n += nwaves) {
        int2 m = meta[n];
        int beg = m.x, end = m.x + m.y;
        float dn = rsqrtf(fmaxf((float)m.y, 1.0f));
        float2 a0 = make_float2(0.f, 0.f), a1 = a0, a2 = a0, a3 = a0;
        int i = beg;
        for (; i + 16 <= end; i += 16) {   // 16 edges, 4 row-group loads in flight
            int s0 = ssrc[i + q],      s1 = ssrc[i + 4 + q];
            int s2 = ssrc[i + 8 + q],  s3 = ssrc[i + 12 + q];
            float2 f0 = __half22float2(ycol[(size_t)s0 * 16]);
            float2 f1 = __half22float2(ycol[(size_t)s1 * 16]);
            float2 f2 = __half22float2(ycol[(size_t)s2 * 16]);
            float2 f3 = __half22float2(ycol[(size_t)s3 * 16]);
            ACC(a0, f0) ACC(a1, f1) ACC(a2, f2) ACC(a3, f3)
        }
        for (; i + 4 <= end; i += 4) {
            int s = ssrc[i + q];
            float2 f = __half22float2(ycol[(size_t)s * 16]);
            ACC(a0, f)
        }
        int rem = end - i;
        if (q < rem) {
            int s = ssrc[i + q];
            float2 f = __half22float2(ycol[(size_t)s * 16]);
            ACC(a1, f)
        }
        float2 t;
        t.x = (a0.x + a1.x) + (a2.x + a3.x);
        t.y = (a0.y + a1.y) + (a2.y + a3.y);
        t.x += __shfl(t.x, lane ^ 16); t.y += __shfl(t.y, lane ^ 16);
        t.x += __shfl(t.x, lane ^ 32); t.y += __shfl(t.y, lane ^ 32);
        if (q == 0) {
            vfloat2 o;
            o.x = fmaf(t.x, dn, b2.x);
            o.y = fmaf(t.y, dn, b2.y);
            __builtin_nontemporal_store(o, (vfloat2*)(out + (size_t)n * D + (pass << 5)) + c);
        }
    }
#undef ACC
}

extern "C" void kernel_launch(void* const* d_in, const int* in_sizes, int n_in,
                              void* d_out, int out_size, void* d_ws, size_t ws_size,
                              hipStream_t stream) {
    const float* x   = (const float*)d_in[0];
    const int*   src = (const int*)d_in[1];
    const int*   dst = (const int*)d_in[2];
    const float* W   = (const float*)d_in[3];
    const float* b   = (const float*)d_in[4];
    float* out = (float*)d_out;

    char* ws = (char*)d_ws;
    int*          ctr   = (int*)(ws + CTR_OFF);
    int*          gate  = (int*)(ws + GATE_OFF);
    int2*         meta  = (int2*)(ws + META_OFF);
    float*        snorm = (float*)(ws + SNORM_OFF);
    int*          ssrc  = (int*)(ws + SSRC_OFF);
    uchar4*       occ4  = (uchar4*)(ws + OCC_OFF);
    unsigned int* part  = (unsigned int*)(ws + PART_OFF);
    __half*       yA    = (__half*)(ws + YA_OFF);
    __half*       yB    = (__half*)(ws + YB_OFF);

    const int4* src4 = (const int4*)src;
    const int4* dst4 = (const int4*)dst;

    degree_occ_kernel<<<2 * SLICES, 256, 0, stream>>>(src4, dst4, part, occ4, ctr, gate);
    mega_kernel<<<MBLK, 256, 0, stream>>>(src4, dst4, occ4, part, meta, snorm,
                                          ctr, gate, ssrc, x, W, yA, yB);
    gather_kernel<<<GBLK, 256, 0, stream>>>((const __half2*)yA, (const __half2*)yB,
                                            ssrc, meta, b, out);
}

// Round 10
// 151.650 us; speedup vs baseline: 1.5182x; 1.5182x over previous
//
#include <hip/hip_runtime.h>
#include <hip/hip_fp16.h>

#define N_NODES 50000
#define N_EDGES 800000
#define D 64

#define SLICES 100                 // edge slices per role (src/dst)
#define I4S    2000                // int4 per slice (8000 edges)
#define NI4    200000              // total int4 per role
#define NWORDS 12512               // ceil(50000/4)=12500, padded to /4

typedef float vfloat2 __attribute__((ext_vector_type(2)));

// ---------------------------------------------------------------------------
// Workspace layout (bytes), ~21 MB, offsets 256-aligned:
//   [0,        4)          ctr    : int (scan counter; zeroed by degree pass)
//   [256,      400256)     meta   : int2[N_NODES]  (.x = CSR base, .y = indeg)
//   [400384,   600384)     snorm  : float[N_NODES]
//   [600576,   3800576)    ssrc   : int[N_EDGES]   src ids grouped by dst
//   [3800576,  4600576)    occ    : uchar[N_EDGES] within-slice occurrence
//   [4600832,  14610432)   partial: uint[200][NWORDS] byte hists -> prefixes
//   [14610432, 17810432)   yA     : half[N_NODES*32] features  0..31
//   [17810688, 21010688)   yB     : half[N_NODES*32] features 32..63
// ---------------------------------------------------------------------------
#define CTR_OFF    0
#define META_OFF   256
#define SNORM_OFF  400384
#define SSRC_OFF   600576
#define OCC_OFF    3800576
#define PART_OFF   4600832
#define YA_OFF     14610432
#define YB_OFF     17810688

// ---------------------------------------------------------------------------
// Pass 1: per-slice byte-packed degree histograms in LDS (no fabric atomics).
// dst-role blocks also record each edge's within-slice occurrence byte
// (the atomicAdd return) into occ[] so the fill pass needs no histogram.
// Block b: role = b&1 (0=src/outdeg, 1=dst/indeg), slice = b>>1.
// Block 0 zeroes the scan counter (replaces the memset dispatch).
// ---------------------------------------------------------------------------
__global__ __launch_bounds__(256) void degree_occ_kernel(const int4* __restrict__ src4,
                                                         const int4* __restrict__ dst4,
                                                         unsigned int* __restrict__ partial,
                                                         uchar4* __restrict__ occ4,
                                                         int* __restrict__ ctr) {
    __shared__ unsigned int hist[NWORDS];
    int tid = threadIdx.x;
    if (blockIdx.x == 0 && tid == 0) *ctr = 0;
    uint4* h4 = (uint4*)hist;
    for (int i = tid; i < NWORDS / 4; i += 256) h4[i] = make_uint4(0, 0, 0, 0);
    __syncthreads();

    int role  = blockIdx.x & 1;
    int slice = blockIdx.x >> 1;
    int beg = slice * I4S, end = beg + I4S;
    if (role == 0) {
        for (int i = beg + tid; i < end; i += 256) {
            int4 v = src4[i];
            atomicAdd(&hist[v.x >> 2], 1u << ((v.x & 3) * 8));
            atomicAdd(&hist[v.y >> 2], 1u << ((v.y & 3) * 8));
            atomicAdd(&hist[v.z >> 2], 1u << ((v.z & 3) * 8));
            atomicAdd(&hist[v.w >> 2], 1u << ((v.w & 3) * 8));
        }
    } else {
        for (int i = beg + tid; i < end; i += 256) {
            int4 v = dst4[i];
            unsigned int o0 = (atomicAdd(&hist[v.x >> 2], 1u << ((v.x & 3) * 8)) >> ((v.x & 3) * 8)) & 0xFFu;
            unsigned int o1 = (atomicAdd(&hist[v.y >> 2], 1u << ((v.y & 3) * 8)) >> ((v.y & 3) * 8)) & 0xFFu;
            unsigned int o2 = (atomicAdd(&hist[v.z >> 2], 1u << ((v.z & 3) * 8)) >> ((v.z & 3) * 8)) & 0xFFu;
            unsigned int o3 = (atomicAdd(&hist[v.w >> 2], 1u << ((v.w & 3) * 8)) >> ((v.w & 3) * 8)) & 0xFFu;
            occ4[i] = make_uchar4((unsigned char)o0, (unsigned char)o1,
                                  (unsigned char)o2, (unsigned char)o3);
        }
    }
    __syncthreads();

    uint4* p4 = (uint4*)(partial + (size_t)blockIdx.x * NWORDS);
    for (int i = tid; i < NWORDS / 4; i += 256) p4[i] = h4[i];
}

// Pass 2 (fused merge + scan): thread per word (4 nodes). Sums packed degrees
// over all slices, rewrites dst-role partials in place to per-slice EXCLUSIVE
// prefixes (byte adds; cumulative <= indeg < 255, no carry), then wave-scans
// the 4-node sums for CSR bases; writes meta=(base,indeg) and snorm.
__global__ __launch_bounds__(256) void merge_scan_kernel(unsigned int* __restrict__ partial,
                                                         int2* __restrict__ meta,
                                                         float* __restrict__ snorm,
                                                         int* __restrict__ ctr) {
    int w = blockIdx.x * blockDim.x + threadIdx.x;
    int lane = threadIdx.x & 63;
    unsigned int accin = 0, accout = 0;
    if (w < 12500) {
        unsigned int* po = partial + w;            // src role: slot 2s
        unsigned int* pd = partial + NWORDS + w;   // dst role: slot 2s+1
#pragma unroll 4
        for (int s = 0; s < SLICES; s++) {
            size_t off = (size_t)(2 * s) * NWORDS;
            accout += po[off];
            unsigned int v = pd[off];
            pd[off] = accin;                       // exclusive prefix before slice s
            accin += v;
        }
    }
    int d0 = accin & 0xFF, d1 = (accin >> 8) & 0xFF,
        d2 = (accin >> 16) & 0xFF, d3 = (accin >> 24) & 0xFF;
    int tsum = d0 + d1 + d2 + d3;
    int run = tsum;  // inclusive wave scan of per-thread totals
#pragma unroll
    for (int off = 1; off < 64; off <<= 1) {
        int v = __shfl_up(run, off);
        if (lane >= off) run += v;
    }
    int wtot = __shfl(run, 63);
    int wbase = 0;
    if (lane == 63) wbase = atomicAdd(ctr, wtot);
    wbase = __shfl(wbase, 63);
    if (w < 12500) {
        int b0 = wbase + run - tsum;
        int b1 = b0 + d0, b2 = b1 + d1, b3 = b2 + d2;
        ((int4*)meta)[2 * w]     = make_int4(b0, d0, b1, d1);
        ((int4*)meta)[2 * w + 1] = make_int4(b2, d2, b3, d3);
        int o0 = accout & 0xFF, o1 = (accout >> 8) & 0xFF,
            o2 = (accout >> 16) & 0xFF, o3 = (accout >> 24) & 0xFF;
        ((float4*)snorm)[w] = make_float4(rsqrtf(fmaxf((float)o0, 1.f)),
                                          rsqrtf(fmaxf((float)o1, 1.f)),
                                          rsqrtf(fmaxf((float)o2, 1.f)),
                                          rsqrtf(fmaxf((float)o3, 1.f)));
    }
}

// Pass 3 (fused fill + y): two independent streaming phases in one dispatch.
// Fill: fully parallel, no LDS, no atomics — p = meta.x + slice prefix + occ.
// Y:    y = (x * snorm) @ W stored fp16, split into two feature-half arrays
//       yA (features 0..31) / yB (32..63), each 3.2 MB (per-XCD-L2-sized).
#define FYBLK 1024
__global__ __launch_bounds__(256, 4) void filly_kernel(const int4* __restrict__ src4,
                                                       const int4* __restrict__ dst4,
                                                       const uchar4* __restrict__ occ4,
                                                       const unsigned int* __restrict__ partial,
                                                       const int2* __restrict__ meta,
                                                       int* __restrict__ ssrc,
                                                       const float* __restrict__ x,
                                                       const float* __restrict__ snorm,
                                                       const float* __restrict__ W,
                                                       __half* __restrict__ yA,
                                                       __half* __restrict__ yB) {
    int tid = blockIdx.x * blockDim.x + threadIdx.x;
    int lane = threadIdx.x & 63;

    if (tid < NI4) {
        int s = tid / I4S;
        const unsigned int* pref = partial + (size_t)(2 * s + 1) * NWORDS;
        int4 sv = src4[tid], tv = dst4[tid];
        uchar4 oc = occ4[tid];
#define FILL_ONE(T, S, O)                                                     \
        {                                                                     \
            int t = (T); int sh = (t & 3) * 8;                                \
            int p = meta[t].x + (int)((pref[t >> 2] >> sh) & 0xFFu) + (int)(O); \
            ssrc[p] = (S);                                                    \
        }
        FILL_ONE(tv.x, sv.x, oc.x)
        FILL_ONE(tv.y, sv.y, oc.y)
        FILL_ONE(tv.z, sv.z, oc.z)
        FILL_ONE(tv.w, sv.w, oc.w)
#undef FILL_ONE
    }

    float Wreg[D];
#pragma unroll
    for (int k = 0; k < D; k++) Wreg[k] = W[k * D + lane];
    __half* yh = (lane < 32) ? yA : yB;   // uniform per half-wave
    int jl = lane & 31;
    int wave = tid >> 6;
    const int nwaves = FYBLK * 4;
    for (int n = wave; n < N_NODES; n += nwaves) {
        float hv = x[(size_t)n * D + lane] * snorm[n];
        int hb = __float_as_int(hv);
        float p0 = 0.f, p1 = 0.f, p2 = 0.f, p3 = 0.f;
#pragma unroll
        for (int k = 0; k < D; k += 4) {
            p0 = fmaf(__int_as_float(__builtin_amdgcn_readlane(hb, k + 0)), Wreg[k + 0], p0);
            p1 = fmaf(__int_as_float(__builtin_amdgcn_readlane(hb, k + 1)), Wreg[k + 1], p1);
            p2 = fmaf(__int_as_float(__builtin_amdgcn_readlane(hb, k + 2)), Wreg[k + 2], p2);
            p3 = fmaf(__int_as_float(__builtin_amdgcn_readlane(hb, k + 3)), Wreg[k + 3], p3);
        }
        yh[(size_t)n * 32 + jl] = __float2half((p0 + p1) + (p2 + p3));
    }
}

// Pass 4: out[n] = rsqrt(indeg) * sum_{in-edges} y[src] + b, by feature half.
// pass = blockIdx&1 (XCD partition of yA/yB). Lane = (q = edge-of-4, c =
// half2 chunk): one wave-load = 4 rows of 64 B; main loop keeps 8 group-loads
// (32 edges) in flight. shfl ^16/^32 reduce; nontemporal float2 stores.
#define GBLK 2048
__global__ __launch_bounds__(256, 8) void gather_kernel(const __half2* __restrict__ yA,
                                                        const __half2* __restrict__ yB,
                                                        const int* __restrict__ ssrc,
                                                        const int2* __restrict__ meta,
                                                        const float* __restrict__ bias,
                                                        float* __restrict__ out) {
    int lane = threadIdx.x & 63;
    int q = lane >> 4;
    int c = lane & 15;
    int pass = blockIdx.x & 1;         // 0 -> yA, 1 -> yB
    int pblk = blockIdx.x >> 1;
    int wave = (pblk << 2) | (threadIdx.x >> 6);
    const int nwaves = (GBLK / 2) * 4;

    float2 b2 = ((const float2*)bias)[(pass << 4) + c];
    const __half2* ycol = (pass ? yB : yA) + c;   // row stride = 16 half2

#define ACC(A, F) { (A).x += (F).x; (A).y += (F).y; }

    for (int n = wave; n < N_NODES; n += nwaves) {
        int2 m = meta[n];
        int beg = m.x, end = m.x + m.y;
        float dn = rsqrtf(fmaxf((float)m.y, 1.0f));
        float2 a0 = make_float2(0.f, 0.f), a1 = a0, a2 = a0, a3 = a0;
        float2 a4 = a0, a5 = a0, a6 = a0, a7 = a0;
        int i = beg;
        for (; i + 32 <= end; i += 32) {   // 32 edges, 8 group-loads in flight
            int s0 = ssrc[i + q],      s1 = ssrc[i + 4 + q];
            int s2 = ssrc[i + 8 + q],  s3 = ssrc[i + 12 + q];
            int s4 = ssrc[i + 16 + q], s5 = ssrc[i + 20 + q];
            int s6 = ssrc[i + 24 + q], s7 = ssrc[i + 28 + q];
            float2 f0 = __half22float2(ycol[(size_t)s0 * 16]);
            float2 f1 = __half22float2(ycol[(size_t)s1 * 16]);
            float2 f2 = __half22float2(ycol[(size_t)s2 * 16]);
            float2 f3 = __half22float2(ycol[(size_t)s3 * 16]);
            float2 f4 = __half22float2(ycol[(size_t)s4 * 16]);
            float2 f5 = __half22float2(ycol[(size_t)s5 * 16]);
            float2 f6 = __half22float2(ycol[(size_t)s6 * 16]);
            float2 f7 = __half22float2(ycol[(size_t)s7 * 16]);
            ACC(a0, f0) ACC(a1, f1) ACC(a2, f2) ACC(a3, f3)
            ACC(a4, f4) ACC(a5, f5) ACC(a6, f6) ACC(a7, f7)
        }
        for (; i + 16 <= end; i += 16) {   // 16 edges, 4 loads
            int s0 = ssrc[i + q],      s1 = ssrc[i + 4 + q];
            int s2 = ssrc[i + 8 + q],  s3 = ssrc[i + 12 + q];
            float2 f0 = __half22float2(ycol[(size_t)s0 * 16]);
            float2 f1 = __half22float2(ycol[(size_t)s1 * 16]);
            float2 f2 = __half22float2(ycol[(size_t)s2 * 16]);
            float2 f3 = __half22float2(ycol[(size_t)s3 * 16]);
            ACC(a0, f0) ACC(a1, f1) ACC(a2, f2) ACC(a3, f3)
        }
        for (; i + 4 <= end; i += 4) {     // 4-edge groups
            int s = ssrc[i + q];
            float2 f = __half22float2(ycol[(size_t)s * 16]);
            ACC(a0, f)
        }
        int rem = end - i;                 // tail < 4 edges
        if (q < rem) {
            int s = ssrc[i + q];
            float2 f = __half22float2(ycol[(size_t)s * 16]);
            ACC(a1, f)
        }
        float2 t;
        t.x = ((a0.x + a1.x) + (a2.x + a3.x)) + ((a4.x + a5.x) + (a6.x + a7.x));
        t.y = ((a0.y + a1.y) + (a2.y + a3.y)) + ((a4.y + a5.y) + (a6.y + a7.y));
        t.x += __shfl(t.x, lane ^ 16); t.y += __shfl(t.y, lane ^ 16);
        t.x += __shfl(t.x, lane ^ 32); t.y += __shfl(t.y, lane ^ 32);
        if (q == 0) {
            vfloat2 o;
            o.x = fmaf(t.x, dn, b2.x);
            o.y = fmaf(t.y, dn, b2.y);
            __builtin_nontemporal_store(o, (vfloat2*)(out + (size_t)n * D + (pass << 5)) + c);
        }
    }
#undef ACC
}

extern "C" void kernel_launch(void* const* d_in, const int* in_sizes, int n_in,
                              void* d_out, int out_size, void* d_ws, size_t ws_size,
                              hipStream_t stream) {
    const float* x   = (const float*)d_in[0];
    const int*   src = (const int*)d_in[1];
    const int*   dst = (const int*)d_in[2];
    const float* W   = (const float*)d_in[3];
    const float* b   = (const float*)d_in[4];
    float* out = (float*)d_out;

    char* ws = (char*)d_ws;
    int*          ctr   = (int*)(ws + CTR_OFF);
    int2*         meta  = (int2*)(ws + META_OFF);
    float*        snorm = (float*)(ws + SNORM_OFF);
    int*          ssrc  = (int*)(ws + SSRC_OFF);
    uchar4*       occ4  = (uchar4*)(ws + OCC_OFF);
    unsigned int* part  = (unsigned int*)(ws + PART_OFF);
    __half*       yA    = (__half*)(ws + YA_OFF);
    __half*       yB    = (__half*)(ws + YB_OFF);

    const int4* src4 = (const int4*)src;
    const int4* dst4 = (const int4*)dst;

    degree_occ_kernel<<<2 * SLICES, 256, 0, stream>>>(src4, dst4, part, occ4, ctr);
    merge_scan_kernel<<<(12500 + 255) / 256, 256, 0, stream>>>(part, meta, snorm, ctr);
    filly_kernel<<<FYBLK, 256, 0, stream>>>(src4, dst4, occ4, part, meta, ssrc,
                                            x, snorm, W, yA, yB);
    gather_kernel<<<GBLK, 256, 0, stream>>>((const __half2*)yA, (const __half2*)yB,
                                            ssrc, meta, b, out);
}